// Round 11
// baseline (3459.397 us; speedup 1.0000x reference)
//
#include <hip/hip_runtime.h>
#include <hip/hip_fp16.h>

#define TT 1024
#define BB 128
#define II 256
#define HH 256
#define NG 768   // 3*H

// Static scratch (ws_size unknown): x bf16, wih^T bf16, gi f16 (bias folded in).
__device__ __align__(16) unsigned short g_xbf[(size_t)TT * BB * II];   // 67 MB
__device__ __align__(16) unsigned short g_wihB[NG * II];               // 384 KB, [n][k]
__device__ __align__(16) _Float16       g_gi[(size_t)TT * BB * NG];    // 201 MB f16

typedef __attribute__((ext_vector_type(8))) short    bfrag;   // 8 bf16 = 4 VGPR
typedef __attribute__((ext_vector_type(8))) _Float16 hfrag;   // 8 f16  = 4 regs
typedef __attribute__((ext_vector_type(4))) float    f32x4;

__device__ __forceinline__ unsigned short f2bf(float f) {
    unsigned u = __float_as_uint(f);
    return (unsigned short)((u + 0x7fffu + ((u >> 16) & 1u)) >> 16);   // RNE
}

// ---------------- phase 1a: x f32 -> bf16 ----------------
__global__ void cvt_x_kernel(const float* __restrict__ x) {
    const int n4 = TT * BB * II / 4;
    for (int i = blockIdx.x * blockDim.x + threadIdx.x; i < n4;
         i += gridDim.x * blockDim.x) {
        float4 v = reinterpret_cast<const float4*>(x)[i];
        ushort4 o;
        o.x = f2bf(v.x); o.y = f2bf(v.y); o.z = f2bf(v.z); o.w = f2bf(v.w);
        reinterpret_cast<ushort4*>(g_xbf)[i] = o;
    }
}

// ---------------- phase 1b: wihT [k][n] f32 -> wihB [n][k] bf16 ----------------
__global__ void cvt_wih_kernel(const float* __restrict__ wihT) {
    const int n = blockIdx.x;    // 0..767
    const int k = threadIdx.x;   // 0..255
    g_wihB[n * II + k] = f2bf(wihT[k * NG + n]);
}

// ---------------- phase 2: gi = x @ wihT + bias  (MFMA bf16, f16 out) ----------------
__global__ void __launch_bounds__(256) gi_gemm_kernel(const float* __restrict__ bias) {
    __shared__ unsigned short Ab[128 * 32];
    __shared__ unsigned short Bb[128 * 32];
    const int tid = threadIdx.x;
    const int mt = blockIdx.x / 6, nt = blockIdx.x % 6;
    const int m0 = mt * 128, n0 = nt * 128;
    const int l = tid & 63, w = tid >> 6;
    const int wr = w >> 1, wc = w & 1;
    const int srow = tid >> 2, scol = (tid & 3) * 8;

    f32x4 acc[4][4] = {};

    for (int ks = 0; ks < 8; ++ks) {
        const int k0 = ks * 32;
        __syncthreads();
        #pragma unroll
        for (int c = 0; c < 2; ++c) {
            const int row = c * 64 + srow;
            *reinterpret_cast<uint4*>(&Ab[row * 32 + scol]) =
                *reinterpret_cast<const uint4*>(&g_xbf[(size_t)(m0 + row) * II + k0 + scol]);
            *reinterpret_cast<uint4*>(&Bb[row * 32 + scol]) =
                *reinterpret_cast<const uint4*>(&g_wihB[(n0 + row) * II + k0 + scol]);
        }
        __syncthreads();
        bfrag af[4], bf[4];
        #pragma unroll
        for (int i = 0; i < 4; ++i) {
            af[i] = *reinterpret_cast<const bfrag*>(
                        &Ab[(wr * 64 + i * 16 + (l & 15)) * 32 + (l >> 4) * 8]);
            bf[i] = *reinterpret_cast<const bfrag*>(
                        &Bb[(wc * 64 + i * 16 + (l & 15)) * 32 + (l >> 4) * 8]);
        }
        #pragma unroll
        for (int mi = 0; mi < 4; ++mi)
            #pragma unroll
            for (int ni = 0; ni < 4; ++ni)
                acc[mi][ni] = __builtin_amdgcn_mfma_f32_16x16x32_bf16(
                                  af[mi], bf[ni], acc[mi][ni], 0, 0, 0);
    }
    #pragma unroll
    for (int mi = 0; mi < 4; ++mi) {
        const int grow = m0 + wr * 64 + mi * 16 + (l >> 4) * 4;
        #pragma unroll
        for (int ni = 0; ni < 4; ++ni) {
            const int gcol = n0 + wc * 64 + ni * 16 + (l & 15);
            const float bv = bias[gcol];
            #pragma unroll
            for (int q = 0; q < 4; ++q)
                g_gi[(size_t)(grow + q) * NG + gcol] = (_Float16)(acc[mi][ni][q] + bv);
        }
    }
}

// ---------------- phase 3: recurrence via MFMA, whh pinned in AGPRs ----------------
// 128 WGs (one batch row) x 512 threads (8 waves, 2/SIMD -> 256 unified
// regs/lane). Wave w owns col-tiles {w, w+8, .., w+40}: 2 tiles per gate,
// lane ln15 (g==0) owns j = 16w+ln15 AND j+128, all 3 gates lane-local ->
// ONE barrier per step, no cross-wave exchange.
//
// r10 lesson: hand-written asm MFMA loses the backend's hazard insertion
// (VALU-write -> MFMA-read wait states) -> silent corruption. gfx950 MFMA
// BUILTINS accept AGPR-class A/B operands natively (ISA section 10), so:
// pin the 48 B-frags into the AGPR half of the unified file with
// asm("" : "+a"(frag)) once at init, then consume with the builtin --
// AGPR residency (the half that sat empty while r2-r9 spilled 60+ MB)
// plus compiler-managed hazards and scheduling.
#define LDB1(T, KT)                                                         \
    hfrag B##T##_##KT;                                                      \
    _Pragma("unroll")                                                       \
    for (int e = 0; e < 8; ++e)                                             \
        B##T##_##KT[e] = (_Float16)whhT[(size_t)((KT) * 32 + g8 + e) * NG + cb##T + ln15]; \
    asm("" : "+a"(B##T##_##KT));

#define LDB8(T) LDB1(T,0) LDB1(T,1) LDB1(T,2) LDB1(T,3) \
                LDB1(T,4) LDB1(T,5) LDB1(T,6) LDB1(T,7)

#define KST(KT)                                                             \
    {                                                                       \
        const hfrag Av = *reinterpret_cast<const hfrag*>(hl + (KT) * 32 + g8); \
        const hfrag A  = (ln15 == 0) ? Av : hz;                             \
        acc0 = __builtin_amdgcn_mfma_f32_16x16x32_f16(A, B0_##KT, acc0, 0, 0, 0); \
        acc1 = __builtin_amdgcn_mfma_f32_16x16x32_f16(A, B1_##KT, acc1, 0, 0, 0); \
        acc2 = __builtin_amdgcn_mfma_f32_16x16x32_f16(A, B2_##KT, acc2, 0, 0, 0); \
        acc3 = __builtin_amdgcn_mfma_f32_16x16x32_f16(A, B3_##KT, acc3, 0, 0, 0); \
        acc4 = __builtin_amdgcn_mfma_f32_16x16x32_f16(A, B4_##KT, acc4, 0, 0, 0); \
        acc5 = __builtin_amdgcn_mfma_f32_16x16x32_f16(A, B5_##KT, acc5, 0, 0, 0); \
    }

__global__ void __launch_bounds__(512)
__attribute__((amdgpu_waves_per_eu(2, 2)))
gru_rec_kernel(
    const float* __restrict__ h0, const float* __restrict__ whhT,
    float* __restrict__ out)
{
    __shared__ __align__(16) _Float16 hbuf[2][HH];   // 1 KB ping-pong h (f16)

    const int tid  = threadIdx.x;
    const int b    = blockIdx.x;
    const int w    = tid >> 6;          // wave 0..7
    const int l    = tid & 63;
    const int ln15 = l & 15;
    const int g8   = (l >> 4) * 8;      // k-sub-chunk base within tile
    // col-tile bases: tiles {w, w+8, w+16, w+24, w+32, w+40} * 16
    const int cb0 = (w)      * 16;      // r, col j1
    const int cb1 = (w + 8)  * 16;      // r, col j2 = j1+128
    const int cb2 = (w + 16) * 16;      // z, j1
    const int cb3 = (w + 24) * 16;      // z, j2
    const int cb4 = (w + 32) * 16;      // n, j1
    const int cb5 = (w + 40) * 16;      // n, j2
    const int jj1 = w * 16 + ln15;      // this lane's first j (on g==0)
    const int jj2 = jj1 + 128;          // second j

    // --- 48 whh B-fragments, loaded once, pinned into AGPR class ---
    LDB8(0) LDB8(1) LDB8(2) LDB8(3) LDB8(4) LDB8(5)

    const hfrag hz = {};

    // --- init LDS row with h0; hprev tracked in-register on g==0 lanes ---
    float hprev1 = h0[b * HH + jj1];
    float hprev2 = h0[b * HH + jj2];
    if (tid < 256) hbuf[0][tid] = (_Float16)h0[b * HH + tid];
    __syncthreads();

    // gi prefetch registers (bias pre-folded), primed for t=0
    const _Float16* gb0 = g_gi + (size_t)b * NG;
    float gR1 = (float)gb0[jj1], gZ1 = (float)gb0[HH + jj1], gN1 = (float)gb0[2 * HH + jj1];
    float gR2 = (float)gb0[jj2], gZ2 = (float)gb0[HH + jj2], gN2 = (float)gb0[2 * HH + jj2];

    for (int t = 0; t < TT; ++t) {
        const _Float16* hl  = hbuf[t & 1];
        _Float16*       hn_ = hbuf[(t & 1) ^ 1];

        // prefetch gi[t+1] (consumed next iteration)
        float nR1 = gR1, nZ1 = gZ1, nN1 = gN1, nR2 = gR2, nZ2 = gZ2, nN2 = gN2;
        if (t + 1 < TT) {
            const _Float16* gn = g_gi + ((size_t)(t + 1) * BB + b) * NG;
            nR1 = (float)gn[jj1]; nZ1 = (float)gn[HH + jj1]; nN1 = (float)gn[2 * HH + jj1];
            nR2 = (float)gn[jj2]; nZ2 = (float)gn[HH + jj2]; nN2 = (float)gn[2 * HH + jj2];
        }

        f32x4 acc0 = {0.f,0.f,0.f,0.f}, acc1 = {0.f,0.f,0.f,0.f};
        f32x4 acc2 = {0.f,0.f,0.f,0.f}, acc3 = {0.f,0.f,0.f,0.f};
        f32x4 acc4 = {0.f,0.f,0.f,0.f}, acc5 = {0.f,0.f,0.f,0.f};
        KST(0) KST(1) KST(2) KST(3) KST(4) KST(5) KST(6) KST(7)

        // epilogue: C row 0 (lanes g==0, col=ln15); two j's per lane
        const float r1 = 1.f / (1.f + __expf(-(acc0[0] + gR1)));
        const float z1 = 1.f / (1.f + __expf(-(acc2[0] + gZ1)));
        const float e1 = __expf(2.f * (gN1 + r1 * acc4[0]));   // tanh
        const float n1 = 1.f - 2.f / (e1 + 1.f);
        const float hv1 = (1.f - z1) * n1 + z1 * hprev1;

        const float r2 = 1.f / (1.f + __expf(-(acc1[0] + gR2)));
        const float z2 = 1.f / (1.f + __expf(-(acc3[0] + gZ2)));
        const float e2 = __expf(2.f * (gN2 + r2 * acc5[0]));
        const float n2 = 1.f - 2.f / (e2 + 1.f);
        const float hv2 = (1.f - z2) * n2 + z2 * hprev2;

        if ((l >> 4) == 0) {
            hprev1 = hv1; hprev2 = hv2;
            hn_[jj1] = (_Float16)hv1;
            hn_[jj2] = (_Float16)hv2;
            if (t == TT - 1) {
                out[b * HH + jj1] = hv1;
                out[b * HH + jj2] = hv2;
            }
        }

        gR1 = nR1; gZ1 = nZ1; gN1 = nN1;
        gR2 = nR2; gZ2 = nZ2; gN2 = nN2;
        __syncthreads();
    }
}

extern "C" void kernel_launch(void* const* d_in, const int* in_sizes, int n_in,
                              void* d_out, int out_size, void* d_ws, size_t ws_size,
                              hipStream_t stream) {
    const float* x    = (const float*)d_in[0];
    const float* h0   = (const float*)d_in[1];
    const float* wihT = (const float*)d_in[2];
    const float* whhT = (const float*)d_in[3];
    const float* bias = (const float*)d_in[4];
    float*       out  = (float*)d_out;

    cvt_x_kernel<<<2048, 256, 0, stream>>>(x);
    cvt_wih_kernel<<<NG, 256, 0, stream>>>(wihT);
    gi_gemm_kernel<<<1024 * 6, 256, 0, stream>>>(bias);
    gru_rec_kernel<<<BB, 512, 0, stream>>>(h0, whhT, out);
}

// Round 12
// 1456.242 us; speedup vs baseline: 2.3756x; 2.3756x over previous
//
#include <hip/hip_runtime.h>
#include <hip/hip_fp16.h>

#define TT 1024
#define BB 128
#define II 256
#define HH 256
#define NG 768   // 3*H

// Static scratch (ws_size unknown): x bf16, wih^T bf16, gi f16 (bias folded in).
__device__ __align__(16) unsigned short g_xbf[(size_t)TT * BB * II];   // 67 MB
__device__ __align__(16) unsigned short g_wihB[NG * II];               // 384 KB, [n][k]
__device__ __align__(16) _Float16       g_gi[(size_t)TT * BB * NG];    // 201 MB f16

typedef __attribute__((ext_vector_type(8))) short    bfrag;   // 8 bf16 = 4 VGPR
typedef __attribute__((ext_vector_type(8))) _Float16 hfrag;   // 8 f16  = 4 regs
typedef __attribute__((ext_vector_type(4))) float    f32x4;

__device__ __forceinline__ unsigned short f2bf(float f) {
    unsigned u = __float_as_uint(f);
    return (unsigned short)((u + 0x7fffu + ((u >> 16) & 1u)) >> 16);   // RNE
}

// ---------------- phase 1a: x f32 -> bf16 ----------------
__global__ void cvt_x_kernel(const float* __restrict__ x) {
    const int n4 = TT * BB * II / 4;
    for (int i = blockIdx.x * blockDim.x + threadIdx.x; i < n4;
         i += gridDim.x * blockDim.x) {
        float4 v = reinterpret_cast<const float4*>(x)[i];
        ushort4 o;
        o.x = f2bf(v.x); o.y = f2bf(v.y); o.z = f2bf(v.z); o.w = f2bf(v.w);
        reinterpret_cast<ushort4*>(g_xbf)[i] = o;
    }
}

// ---------------- phase 1b: wihT [k][n] f32 -> wihB [n][k] bf16 ----------------
__global__ void cvt_wih_kernel(const float* __restrict__ wihT) {
    const int n = blockIdx.x;    // 0..767
    const int k = threadIdx.x;   // 0..255
    g_wihB[n * II + k] = f2bf(wihT[k * NG + n]);
}

// ---------------- phase 2: gi = x @ wihT + bias  (MFMA bf16, f16 out) ----------------
__global__ void __launch_bounds__(256) gi_gemm_kernel(const float* __restrict__ bias) {
    __shared__ unsigned short Ab[128 * 32];
    __shared__ unsigned short Bb[128 * 32];
    const int tid = threadIdx.x;
    const int mt = blockIdx.x / 6, nt = blockIdx.x % 6;
    const int m0 = mt * 128, n0 = nt * 128;
    const int l = tid & 63, w = tid >> 6;
    const int wr = w >> 1, wc = w & 1;
    const int srow = tid >> 2, scol = (tid & 3) * 8;

    f32x4 acc[4][4] = {};

    for (int ks = 0; ks < 8; ++ks) {
        const int k0 = ks * 32;
        __syncthreads();
        #pragma unroll
        for (int c = 0; c < 2; ++c) {
            const int row = c * 64 + srow;
            *reinterpret_cast<uint4*>(&Ab[row * 32 + scol]) =
                *reinterpret_cast<const uint4*>(&g_xbf[(size_t)(m0 + row) * II + k0 + scol]);
            *reinterpret_cast<uint4*>(&Bb[row * 32 + scol]) =
                *reinterpret_cast<const uint4*>(&g_wihB[(n0 + row) * II + k0 + scol]);
        }
        __syncthreads();
        bfrag af[4], bf[4];
        #pragma unroll
        for (int i = 0; i < 4; ++i) {
            af[i] = *reinterpret_cast<const bfrag*>(
                        &Ab[(wr * 64 + i * 16 + (l & 15)) * 32 + (l >> 4) * 8]);
            bf[i] = *reinterpret_cast<const bfrag*>(
                        &Bb[(wc * 64 + i * 16 + (l & 15)) * 32 + (l >> 4) * 8]);
        }
        #pragma unroll
        for (int mi = 0; mi < 4; ++mi)
            #pragma unroll
            for (int ni = 0; ni < 4; ++ni)
                acc[mi][ni] = __builtin_amdgcn_mfma_f32_16x16x32_bf16(
                                  af[mi], bf[ni], acc[mi][ni], 0, 0, 0);
    }
    #pragma unroll
    for (int mi = 0; mi < 4; ++mi) {
        const int grow = m0 + wr * 64 + mi * 16 + (l >> 4) * 4;
        #pragma unroll
        for (int ni = 0; ni < 4; ++ni) {
            const int gcol = n0 + wc * 64 + ni * 16 + (l & 15);
            const float bv = bias[gcol];
            #pragma unroll
            for (int q = 0; q < 4; ++q)
                g_gi[(size_t)(grow + q) * NG + gcol] = (_Float16)(acc[mi][ni][q] + bv);
        }
    }
}

// ---------------- phase 3: recurrence via MFMA ----------------
// 128 WGs (one batch row) x 512 threads (8 waves, 2/SIMD -> HW budget is
// 256 unified regs/lane). Wave w owns col-tiles {w, w+8, .., w+40}: 2
// tiles per gate, lane ln15 (g==0) owns j = 16w+ln15 AND j+128, all 3
// gates lane-local -> ONE barrier per step, no cross-wave exchange.
//
// Register story (r2-r11): the RA ignores amdgpu_waves_per_eu and budgets
// for 2 WGs/CU (512thr -> 128 regs) -- every variant spilled its ~192
// weight regs to scratch and the kernel became an L1/L2 weight-stream.
// The ONE observed exception: __launch_bounds__(N, 1) (r2: granted 204
// arch VGPRs). Need here = 192 frag + 24 acc + ~35 misc = ~251 <= 256.
// So: launch_bounds(512, 1), builtin MFMA (compiler-managed hazards --
// r10's hand-asm corrupted), and no asm class-pins (r11's partial-pin
// fragmented the file: 32/48 frags resident, rest scratch-streamed).
#define LDB1(T, KT)                                                         \
    hfrag B##T##_##KT;                                                      \
    _Pragma("unroll")                                                       \
    for (int e = 0; e < 8; ++e)                                             \
        B##T##_##KT[e] = (_Float16)whhT[(size_t)((KT) * 32 + g8 + e) * NG + cb##T + ln15];

#define LDB8(T) LDB1(T,0) LDB1(T,1) LDB1(T,2) LDB1(T,3) \
                LDB1(T,4) LDB1(T,5) LDB1(T,6) LDB1(T,7)

#define KST(KT)                                                             \
    {                                                                       \
        const hfrag Av = *reinterpret_cast<const hfrag*>(hl + (KT) * 32 + g8); \
        const hfrag A  = (ln15 == 0) ? Av : hz;                             \
        acc0 = __builtin_amdgcn_mfma_f32_16x16x32_f16(A, B0_##KT, acc0, 0, 0, 0); \
        acc1 = __builtin_amdgcn_mfma_f32_16x16x32_f16(A, B1_##KT, acc1, 0, 0, 0); \
        acc2 = __builtin_amdgcn_mfma_f32_16x16x32_f16(A, B2_##KT, acc2, 0, 0, 0); \
        acc3 = __builtin_amdgcn_mfma_f32_16x16x32_f16(A, B3_##KT, acc3, 0, 0, 0); \
        acc4 = __builtin_amdgcn_mfma_f32_16x16x32_f16(A, B4_##KT, acc4, 0, 0, 0); \
        acc5 = __builtin_amdgcn_mfma_f32_16x16x32_f16(A, B5_##KT, acc5, 0, 0, 0); \
    }

__global__ void __launch_bounds__(512, 1) gru_rec_kernel(
    const float* __restrict__ h0, const float* __restrict__ whhT,
    float* __restrict__ out)
{
    __shared__ __align__(16) _Float16 hbuf[2][HH];   // 1 KB ping-pong h (f16)

    const int tid  = threadIdx.x;
    const int b    = blockIdx.x;
    const int w    = tid >> 6;          // wave 0..7
    const int l    = tid & 63;
    const int ln15 = l & 15;
    const int g8   = (l >> 4) * 8;      // k-sub-chunk base within tile
    // col-tile bases: tiles {w, w+8, w+16, w+24, w+32, w+40} * 16
    const int cb0 = (w)      * 16;      // r, col j1
    const int cb1 = (w + 8)  * 16;      // r, col j2 = j1+128
    const int cb2 = (w + 16) * 16;      // z, j1
    const int cb3 = (w + 24) * 16;      // z, j2
    const int cb4 = (w + 32) * 16;      // n, j1
    const int cb5 = (w + 40) * 16;      // n, j2
    const int jj1 = w * 16 + ln15;      // this lane's first j (on g==0)
    const int jj2 = jj1 + 128;          // second j

    // --- 48 whh B-fragments, loaded once ---
    LDB8(0) LDB8(1) LDB8(2) LDB8(3) LDB8(4) LDB8(5)

    const hfrag hz = {};

    // --- init LDS row with h0; hprev tracked in-register on g==0 lanes ---
    float hprev1 = h0[b * HH + jj1];
    float hprev2 = h0[b * HH + jj2];
    if (tid < 256) hbuf[0][tid] = (_Float16)h0[b * HH + tid];
    __syncthreads();

    // gi prefetch registers (bias pre-folded), primed for t=0
    const _Float16* gb0 = g_gi + (size_t)b * NG;
    float gR1 = (float)gb0[jj1], gZ1 = (float)gb0[HH + jj1], gN1 = (float)gb0[2 * HH + jj1];
    float gR2 = (float)gb0[jj2], gZ2 = (float)gb0[HH + jj2], gN2 = (float)gb0[2 * HH + jj2];

    for (int t = 0; t < TT; ++t) {
        const _Float16* hl  = hbuf[t & 1];
        _Float16*       hn_ = hbuf[(t & 1) ^ 1];

        // prefetch gi[t+1] (consumed next iteration)
        float nR1 = gR1, nZ1 = gZ1, nN1 = gN1, nR2 = gR2, nZ2 = gZ2, nN2 = gN2;
        if (t + 1 < TT) {
            const _Float16* gn = g_gi + ((size_t)(t + 1) * BB + b) * NG;
            nR1 = (float)gn[jj1]; nZ1 = (float)gn[HH + jj1]; nN1 = (float)gn[2 * HH + jj1];
            nR2 = (float)gn[jj2]; nZ2 = (float)gn[HH + jj2]; nN2 = (float)gn[2 * HH + jj2];
        }

        f32x4 acc0 = {0.f,0.f,0.f,0.f}, acc1 = {0.f,0.f,0.f,0.f};
        f32x4 acc2 = {0.f,0.f,0.f,0.f}, acc3 = {0.f,0.f,0.f,0.f};
        f32x4 acc4 = {0.f,0.f,0.f,0.f}, acc5 = {0.f,0.f,0.f,0.f};
        KST(0) KST(1) KST(2) KST(3) KST(4) KST(5) KST(6) KST(7)

        // epilogue: C row 0 (lanes g==0, col=ln15); two j's per lane
        const float r1 = 1.f / (1.f + __expf(-(acc0[0] + gR1)));
        const float z1 = 1.f / (1.f + __expf(-(acc2[0] + gZ1)));
        const float e1 = __expf(2.f * (gN1 + r1 * acc4[0]));   // tanh
        const float n1 = 1.f - 2.f / (e1 + 1.f);
        const float hv1 = (1.f - z1) * n1 + z1 * hprev1;

        const float r2 = 1.f / (1.f + __expf(-(acc1[0] + gR2)));
        const float z2 = 1.f / (1.f + __expf(-(acc3[0] + gZ2)));
        const float e2 = __expf(2.f * (gN2 + r2 * acc5[0]));
        const float n2 = 1.f - 2.f / (e2 + 1.f);
        const float hv2 = (1.f - z2) * n2 + z2 * hprev2;

        if ((l >> 4) == 0) {
            hprev1 = hv1; hprev2 = hv2;
            hn_[jj1] = (_Float16)hv1;
            hn_[jj2] = (_Float16)hv2;
            if (t == TT - 1) {
                out[b * HH + jj1] = hv1;
                out[b * HH + jj2] = hv2;
            }
        }

        gR1 = nR1; gZ1 = nZ1; gN1 = nN1;
        gR2 = nR2; gZ2 = nZ2; gN2 = nN2;
        __syncthreads();
    }
}

extern "C" void kernel_launch(void* const* d_in, const int* in_sizes, int n_in,
                              void* d_out, int out_size, void* d_ws, size_t ws_size,
                              hipStream_t stream) {
    const float* x    = (const float*)d_in[0];
    const float* h0   = (const float*)d_in[1];
    const float* wihT = (const float*)d_in[2];
    const float* whhT = (const float*)d_in[3];
    const float* bias = (const float*)d_in[4];
    float*       out  = (float*)d_out;

    cvt_x_kernel<<<2048, 256, 0, stream>>>(x);
    cvt_wih_kernel<<<NG, 256, 0, stream>>>(wihT);
    gi_gemm_kernel<<<1024 * 6, 256, 0, stream>>>(bias);
    gru_rec_kernel<<<BB, 512, 0, stream>>>(h0, whhT, out);
}

// Round 13
// 1455.839 us; speedup vs baseline: 2.3762x; 1.0003x over previous
//
#include <hip/hip_runtime.h>
#include <hip/hip_fp16.h>

#define TT 1024
#define BB 128
#define II 256
#define HH 256
#define NG 768   // 3*H

// Static scratch (ws_size unknown): x bf16, wih^T bf16, gi f16 (bias folded in).
__device__ __align__(16) unsigned short g_xbf[(size_t)TT * BB * II];   // 67 MB
__device__ __align__(16) unsigned short g_wihB[NG * II];               // 384 KB, [n][k]
__device__ __align__(16) _Float16       g_gi[(size_t)TT * BB * NG];    // 201 MB f16

typedef __attribute__((ext_vector_type(8))) short    bfrag;   // 8 bf16 = 4 VGPR
typedef __attribute__((ext_vector_type(8))) _Float16 hfrag;   // 8 f16  = 4 regs
typedef __attribute__((ext_vector_type(4))) float    f32x4;

__device__ __forceinline__ unsigned short f2bf(float f) {
    unsigned u = __float_as_uint(f);
    return (unsigned short)((u + 0x7fffu + ((u >> 16) & 1u)) >> 16);   // RNE
}

// ---------------- phase 1a: x f32 -> bf16 ----------------
__global__ void cvt_x_kernel(const float* __restrict__ x) {
    const int n4 = TT * BB * II / 4;
    for (int i = blockIdx.x * blockDim.x + threadIdx.x; i < n4;
         i += gridDim.x * blockDim.x) {
        float4 v = reinterpret_cast<const float4*>(x)[i];
        ushort4 o;
        o.x = f2bf(v.x); o.y = f2bf(v.y); o.z = f2bf(v.z); o.w = f2bf(v.w);
        reinterpret_cast<ushort4*>(g_xbf)[i] = o;
    }
}

// ---------------- phase 1b: wihT [k][n] f32 -> wihB [n][k] bf16 ----------------
__global__ void cvt_wih_kernel(const float* __restrict__ wihT) {
    const int n = blockIdx.x;    // 0..767
    const int k = threadIdx.x;   // 0..255
    g_wihB[n * II + k] = f2bf(wihT[k * NG + n]);
}

// ---------------- phase 2: gi = x @ wihT + bias  (MFMA bf16, f16 out) ----------------
__global__ void __launch_bounds__(256) gi_gemm_kernel(const float* __restrict__ bias) {
    __shared__ unsigned short Ab[128 * 32];
    __shared__ unsigned short Bb[128 * 32];
    const int tid = threadIdx.x;
    const int mt = blockIdx.x / 6, nt = blockIdx.x % 6;
    const int m0 = mt * 128, n0 = nt * 128;
    const int l = tid & 63, w = tid >> 6;
    const int wr = w >> 1, wc = w & 1;
    const int srow = tid >> 2, scol = (tid & 3) * 8;

    f32x4 acc[4][4] = {};

    for (int ks = 0; ks < 8; ++ks) {
        const int k0 = ks * 32;
        __syncthreads();
        #pragma unroll
        for (int c = 0; c < 2; ++c) {
            const int row = c * 64 + srow;
            *reinterpret_cast<uint4*>(&Ab[row * 32 + scol]) =
                *reinterpret_cast<const uint4*>(&g_xbf[(size_t)(m0 + row) * II + k0 + scol]);
            *reinterpret_cast<uint4*>(&Bb[row * 32 + scol]) =
                *reinterpret_cast<const uint4*>(&g_wihB[(n0 + row) * II + k0 + scol]);
        }
        __syncthreads();
        bfrag af[4], bf[4];
        #pragma unroll
        for (int i = 0; i < 4; ++i) {
            af[i] = *reinterpret_cast<const bfrag*>(
                        &Ab[(wr * 64 + i * 16 + (l & 15)) * 32 + (l >> 4) * 8]);
            bf[i] = *reinterpret_cast<const bfrag*>(
                        &Bb[(wc * 64 + i * 16 + (l & 15)) * 32 + (l >> 4) * 8]);
        }
        #pragma unroll
        for (int mi = 0; mi < 4; ++mi)
            #pragma unroll
            for (int ni = 0; ni < 4; ++ni)
                acc[mi][ni] = __builtin_amdgcn_mfma_f32_16x16x32_bf16(
                                  af[mi], bf[ni], acc[mi][ni], 0, 0, 0);
    }
    #pragma unroll
    for (int mi = 0; mi < 4; ++mi) {
        const int grow = m0 + wr * 64 + mi * 16 + (l >> 4) * 4;
        #pragma unroll
        for (int ni = 0; ni < 4; ++ni) {
            const int gcol = n0 + wc * 64 + ni * 16 + (l & 15);
            const float bv = bias[gcol];
            #pragma unroll
            for (int q = 0; q < 4; ++q)
                g_gi[(size_t)(grow + q) * NG + gcol] = (_Float16)(acc[mi][ni][q] + bv);
        }
    }
}

// ---------------- phase 3: recurrence via MFMA ----------------
// 128 WGs (one batch row) x 512 threads (8 waves). Wave w owns col-tiles
// {w, w+8, .., w+40}: 2 tiles per gate, lane ln15 (g==0) owns j = 16w+ln15
// AND j+128, all 3 gates lane-local -> ONE barrier per step.
//
// Register story (r2-r12): the RA's VGPR budget is derived from the
// compile-time occupancy bound, which is computed from the most
// constraining VISIBLE resource. With tiny LDS the backend assumes 2+
// WGs/CU may co-reside -> caps at 128 regs/lane -> our 192 weight regs
// spill to scratch (WRITE_SIZE 37-69 MB in every round; kernel becomes a
// 1.3-3.3 us/step scratch/L2 weight stream). The one kernel that got >128
// regs (r2: 204) had 48 KB LDS. So: declare an 84 KB LDS pad (> 160/2 KB
// -> compile-time occupancy = 1 WG/CU = 2 waves/SIMD -> 256-reg budget).
// Our grid is 128 WGs on 256 CUs, so 1 WG/CU costs nothing at runtime.
// Need = 192 frag + 24 acc + ~25 misc = ~241 <= 256.
#define LDB1(T, KT)                                                         \
    hfrag B##T##_##KT;                                                      \
    _Pragma("unroll")                                                       \
    for (int e = 0; e < 8; ++e)                                             \
        B##T##_##KT[e] = (_Float16)whhT[(size_t)((KT) * 32 + g8 + e) * NG + cb##T + ln15];

#define LDB8(T) LDB1(T,0) LDB1(T,1) LDB1(T,2) LDB1(T,3) \
                LDB1(T,4) LDB1(T,5) LDB1(T,6) LDB1(T,7)

#define KST(KT)                                                             \
    {                                                                       \
        const hfrag Av = *reinterpret_cast<const hfrag*>(hl + (KT) * 32 + g8); \
        const hfrag A  = (ln15 == 0) ? Av : hz;                             \
        acc0 = __builtin_amdgcn_mfma_f32_16x16x32_f16(A, B0_##KT, acc0, 0, 0, 0); \
        acc1 = __builtin_amdgcn_mfma_f32_16x16x32_f16(A, B1_##KT, acc1, 0, 0, 0); \
        acc2 = __builtin_amdgcn_mfma_f32_16x16x32_f16(A, B2_##KT, acc2, 0, 0, 0); \
        acc3 = __builtin_amdgcn_mfma_f32_16x16x32_f16(A, B3_##KT, acc3, 0, 0, 0); \
        acc4 = __builtin_amdgcn_mfma_f32_16x16x32_f16(A, B4_##KT, acc4, 0, 0, 0); \
        acc5 = __builtin_amdgcn_mfma_f32_16x16x32_f16(A, B5_##KT, acc5, 0, 0, 0); \
    }

__global__ void __launch_bounds__(512, 1) gru_rec_kernel(
    const float* __restrict__ h0, const float* __restrict__ whhT,
    float* __restrict__ out)
{
    __shared__ __align__(16) _Float16 hbuf[2][HH];   // 1 KB ping-pong h (f16)
    __shared__ char lds_pad[84 * 1024];              // occupancy-shaping pad

    const int tid  = threadIdx.x;
    const int b    = blockIdx.x;
    const int w    = tid >> 6;          // wave 0..7
    const int l    = tid & 63;
    const int ln15 = l & 15;
    const int g8   = (l >> 4) * 8;      // k-sub-chunk base within tile
    // col-tile bases: tiles {w, w+8, w+16, w+24, w+32, w+40} * 16
    const int cb0 = (w)      * 16;      // r, col j1
    const int cb1 = (w + 8)  * 16;      // r, col j2 = j1+128
    const int cb2 = (w + 16) * 16;      // z, j1
    const int cb3 = (w + 24) * 16;      // z, j2
    const int cb4 = (w + 32) * 16;      // n, j1
    const int cb5 = (w + 40) * 16;      // n, j2
    const int jj1 = w * 16 + ln15;      // this lane's first j (on g==0)
    const int jj2 = jj1 + 128;          // second j

    // keep the pad allocated (one volatile store; never read)
    ((volatile char*)lds_pad)[tid] = 0;

    // --- 48 whh B-fragments, loaded once ---
    LDB8(0) LDB8(1) LDB8(2) LDB8(3) LDB8(4) LDB8(5)

    const hfrag hz = {};

    // --- init LDS row with h0; hprev tracked in-register on g==0 lanes ---
    float hprev1 = h0[b * HH + jj1];
    float hprev2 = h0[b * HH + jj2];
    if (tid < 256) hbuf[0][tid] = (_Float16)h0[b * HH + tid];
    __syncthreads();

    // gi prefetch registers (bias pre-folded), primed for t=0
    const _Float16* gb0 = g_gi + (size_t)b * NG;
    float gR1 = (float)gb0[jj1], gZ1 = (float)gb0[HH + jj1], gN1 = (float)gb0[2 * HH + jj1];
    float gR2 = (float)gb0[jj2], gZ2 = (float)gb0[HH + jj2], gN2 = (float)gb0[2 * HH + jj2];

    for (int t = 0; t < TT; ++t) {
        const _Float16* hl  = hbuf[t & 1];
        _Float16*       hn_ = hbuf[(t & 1) ^ 1];

        // prefetch gi[t+1] (consumed next iteration)
        float nR1 = gR1, nZ1 = gZ1, nN1 = gN1, nR2 = gR2, nZ2 = gZ2, nN2 = gN2;
        if (t + 1 < TT) {
            const _Float16* gn = g_gi + ((size_t)(t + 1) * BB + b) * NG;
            nR1 = (float)gn[jj1]; nZ1 = (float)gn[HH + jj1]; nN1 = (float)gn[2 * HH + jj1];
            nR2 = (float)gn[jj2]; nZ2 = (float)gn[HH + jj2]; nN2 = (float)gn[2 * HH + jj2];
        }

        f32x4 acc0 = {0.f,0.f,0.f,0.f}, acc1 = {0.f,0.f,0.f,0.f};
        f32x4 acc2 = {0.f,0.f,0.f,0.f}, acc3 = {0.f,0.f,0.f,0.f};
        f32x4 acc4 = {0.f,0.f,0.f,0.f}, acc5 = {0.f,0.f,0.f,0.f};
        KST(0) KST(1) KST(2) KST(3) KST(4) KST(5) KST(6) KST(7)

        // epilogue: C row 0 (lanes g==0, col=ln15); two j's per lane
        const float r1 = 1.f / (1.f + __expf(-(acc0[0] + gR1)));
        const float z1 = 1.f / (1.f + __expf(-(acc2[0] + gZ1)));
        const float e1 = __expf(2.f * (gN1 + r1 * acc4[0]));   // tanh
        const float n1 = 1.f - 2.f / (e1 + 1.f);
        const float hv1 = (1.f - z1) * n1 + z1 * hprev1;

        const float r2 = 1.f / (1.f + __expf(-(acc1[0] + gR2)));
        const float z2 = 1.f / (1.f + __expf(-(acc3[0] + gZ2)));
        const float e2 = __expf(2.f * (gN2 + r2 * acc5[0]));
        const float n2 = 1.f - 2.f / (e2 + 1.f);
        const float hv2 = (1.f - z2) * n2 + z2 * hprev2;

        if ((l >> 4) == 0) {
            hprev1 = hv1; hprev2 = hv2;
            hn_[jj1] = (_Float16)hv1;
            hn_[jj2] = (_Float16)hv2;
            if (t == TT - 1) {
                out[b * HH + jj1] = hv1;
                out[b * HH + jj2] = hv2;
            }
        }

        gR1 = nR1; gZ1 = nZ1; gN1 = nN1;
        gR2 = nR2; gZ2 = nZ2; gN2 = nN2;
        __syncthreads();
    }
}

extern "C" void kernel_launch(void* const* d_in, const int* in_sizes, int n_in,
                              void* d_out, int out_size, void* d_ws, size_t ws_size,
                              hipStream_t stream) {
    const float* x    = (const float*)d_in[0];
    const float* h0   = (const float*)d_in[1];
    const float* wihT = (const float*)d_in[2];
    const float* whhT = (const float*)d_in[3];
    const float* bias = (const float*)d_in[4];
    float*       out  = (float*)d_out;

    cvt_x_kernel<<<2048, 256, 0, stream>>>(x);
    cvt_wih_kernel<<<NG, 256, 0, stream>>>(wihT);
    gi_gemm_kernel<<<1024 * 6, 256, 0, stream>>>(bias);
    gru_rec_kernel<<<BB, 512, 0, stream>>>(h0, whhT, out);
}